// Round 1
// baseline (341.462 us; speedup 1.0000x reference)
//
#include <hip/hip_runtime.h>
#include <math.h>

// Shapes: B=8, T=16, H=64, W=64, D=256, DK=128, TOP_K=4
// pixels N = B*H*W = 32768 (4096 per batch)
//
// Factorization: out = (sum_t attn_t * hist_t) @ (Wv@Wo)
//                score_t = (q @ (Wq@Wk^T)) . hist_t / sqrt(128)
// => hist read exactly once; score path kept fully fp32 (top-k selection is
//    precision-critical), V-path also fp32 here.

// ---------------- Kernel P: M1 = Wq@Wk^T, M2 = Wv@Wo (256x256 each) -------
__global__ __launch_bounds__(256) void precompute_weights(
    const float* __restrict__ Wq, const float* __restrict__ Wk,
    const float* __restrict__ Wv, const float* __restrict__ Wo,
    float* __restrict__ M1, float* __restrict__ M2) {
  __shared__ float rowbuf[128];
  int bid = blockIdx.x, tid = threadIdx.x;
  if (bid < 256) {
    // M1[bid][j] = sum_k Wq[bid,k] * Wk[j,k]
    if (tid < 128) rowbuf[tid] = Wq[bid * 128 + tid];
    __syncthreads();
    const float4* Wk4 = (const float4*)Wk;
    const float4* rb4 = (const float4*)rowbuf;
    float acc = 0.f;
#pragma unroll 8
    for (int k4 = 0; k4 < 32; ++k4) {
      float4 a = rb4[k4];
      float4 b = Wk4[tid * 32 + k4];
      acc = fmaf(a.x, b.x, acc); acc = fmaf(a.y, b.y, acc);
      acc = fmaf(a.z, b.z, acc); acc = fmaf(a.w, b.w, acc);
    }
    M1[bid * 256 + tid] = acc;
  } else {
    // M2[d][e] = sum_k Wv[d,k] * Wo[k,e]
    int d = bid - 256;
    if (tid < 128) rowbuf[tid] = Wv[d * 128 + tid];
    __syncthreads();
    float acc = 0.f;
#pragma unroll 8
    for (int k = 0; k < 128; ++k)
      acc = fmaf(rowbuf[k], Wo[k * 256 + tid], acc);
    M2[d * 256 + tid] = acc;
  }
}

// ---------------- GEMM: C[32768x256] = A[32768x256] @ B[256x256] ----------
// 64 rows per block. In-place safe (A may equal C): tile is fully staged to
// LDS before any store, and each block touches only its own 64 rows.
__global__ __launch_bounds__(256) void gemm_32768x256x256(
    const float* A, const float* B, float* C) {
  __shared__ float As[64][257];  // stride 257: 2-way max bank aliasing (free)
  int tid = threadIdx.x;
  size_t r0 = (size_t)blockIdx.x * 64;
  const float* Ab = A + r0 * 256;
  for (int i = tid; i < 64 * 256; i += 256)
    As[i >> 8][i & 255] = Ab[i];
  __syncthreads();
  int ei = tid & 63;  // 4-col group
  int ri = tid >> 6;  // 16-row group
  float4 acc[16];
#pragma unroll
  for (int j = 0; j < 16; ++j) acc[j] = make_float4(0.f, 0.f, 0.f, 0.f);
  const float4* B4 = (const float4*)B;
#pragma unroll 4
  for (int d = 0; d < 256; ++d) {
    float4 bv = B4[d * 64 + ei];
#pragma unroll
    for (int j = 0; j < 16; ++j) {
      float a = As[ri * 16 + j][d];
      acc[j].x = fmaf(a, bv.x, acc[j].x);
      acc[j].y = fmaf(a, bv.y, acc[j].y);
      acc[j].z = fmaf(a, bv.z, acc[j].z);
      acc[j].w = fmaf(a, bv.w, acc[j].w);
    }
  }
  float4* C4 = (float4*)(C + r0 * 256);
#pragma unroll
  for (int j = 0; j < 16; ++j)
    C4[(ri * 16 + j) * 64 + ei] = acc[j];
}

// ---------------- Main: scores -> exact top-4 -> softmax -> hbar ----------
// Block = 256 thr (4 waves), 4 pixels per block (wave p owns pixel p).
// hist tile [16][4][256] f32 staged once in LDS (64 KB) and reused for both
// the score pass and the hbar pass.
__global__ __launch_bounds__(256) void attn_main(
    const float* __restrict__ hist, const float* __restrict__ QM,
    float* __restrict__ HBAR) {
  __shared__ float4 histT[16 * 4 * 64];  // [t][p][64] float4 = 64 KB
  __shared__ float4 qmS[4 * 64];         // 4 KB
  __shared__ float scoresS[4][16];
  __shared__ float attnS[4][16];

  int tid = threadIdx.x;
  int pix0 = blockIdx.x * 4;
  int b = pix0 >> 12;     // 4096 pixels per batch
  int off = pix0 & 4095;  // pixel offset within batch (h*64+w)

  // Stage hist tile: 16 chunks (one per t) of 4 KB, each contiguous.
  const float4* H4 = (const float4*)hist;
  size_t base_b = (size_t)b * 16 * 4096 * 64 + (size_t)off * 64;  // float4 units
  for (int i = tid; i < 4096; i += 256) {
    int t = i >> 8;
    int rem = i & 255;
    histT[i] = H4[base_b + (size_t)t * (4096 * 64) + rem];
  }
  // Stage qm tile (4 pixels x 256 = 256 float4, contiguous)
  qmS[tid] = ((const float4*)QM)[(size_t)pix0 * 64 + tid];
  __syncthreads();

  int p = tid >> 6;  // wave id == pixel id
  int l = tid & 63;

  // ---- scores: part[t] = <qm_p, hist[t,p]> (butterfly-reduced over wave)
  float4 q = qmS[p * 64 + l];
  float part[16];
#pragma unroll
  for (int t = 0; t < 16; ++t) {
    float4 h = histT[(t * 4 + p) * 64 + l];
    float s = h.x * q.x;
    s = fmaf(h.y, q.y, s);
    s = fmaf(h.z, q.z, s);
    s = fmaf(h.w, q.w, s);
    part[t] = s;
  }
#pragma unroll
  for (int sh = 1; sh < 64; sh <<= 1) {
#pragma unroll
    for (int t = 0; t < 16; ++t) part[t] += __shfl_xor(part[t], sh);
  }
  if (l < 16) scoresS[p][l] = part[l] / sqrtf(128.0f);
  __syncthreads();

  // ---- top-4 (exact lax.top_k semantics incl. ties) + decay bias + softmax
  // Done by wave 0: lane = pixel*16 + t.
  if (tid < 64) {
    int pp = tid >> 4, t = tid & 15;
    float s = scoresS[pp][t];
    unsigned long long grp = 0xFFFFull << (pp * 16);
    float work = s;
    bool chosen = false;
#pragma unroll
    for (int r = 0; r < 4; ++r) {
      float m = work;
      m = fmaxf(m, __shfl_xor(m, 1));
      m = fmaxf(m, __shfl_xor(m, 2));
      m = fmaxf(m, __shfl_xor(m, 4));
      m = fmaxf(m, __shfl_xor(m, 8));
      unsigned long long bal = __ballot(work == m) & grp;
      int sel = __ffsll(bal) - 1;  // lowest index among tied maxima
      if (tid == sel) {
        chosen = true;
        work = -INFINITY;
      }
    }
    float bias = logf(powf(0.95f, (float)(16 - t)) + 1e-10f);
    float earg = chosen ? (s + bias) : -INFINITY;
    float M = earg;
    M = fmaxf(M, __shfl_xor(M, 1));
    M = fmaxf(M, __shfl_xor(M, 2));
    M = fmaxf(M, __shfl_xor(M, 4));
    M = fmaxf(M, __shfl_xor(M, 8));
    float ex = chosen ? expf(earg - M) : 0.0f;
    float Z = ex;
    Z += __shfl_xor(Z, 1);
    Z += __shfl_xor(Z, 2);
    Z += __shfl_xor(Z, 4);
    Z += __shfl_xor(Z, 8);
    attnS[pp][t] = ex / Z;
  }
  __syncthreads();

  // ---- hbar_p = sum_t attn[p][t] * hist[t,p]  (skip the 12 zero weights)
  float4 acc = make_float4(0.f, 0.f, 0.f, 0.f);
#pragma unroll
  for (int t = 0; t < 16; ++t) {
    float a = attnS[p][t];  // wave-uniform
    if (a != 0.0f) {
      float4 h = histT[(t * 4 + p) * 64 + l];
      acc.x = fmaf(a, h.x, acc.x);
      acc.y = fmaf(a, h.y, acc.y);
      acc.z = fmaf(a, h.z, acc.z);
      acc.w = fmaf(a, h.w, acc.w);
    }
  }
  ((float4*)HBAR)[(size_t)(pix0 + p) * 64 + l] = acc;
}

// --------------------------------------------------------------------------
extern "C" void kernel_launch(void* const* d_in, const int* in_sizes, int n_in,
                              void* d_out, int out_size, void* d_ws,
                              size_t ws_size, hipStream_t stream) {
  const float* query = (const float*)d_in[0];  // [8,64,64,256]
  const float* hist = (const float*)d_in[1];   // [8,16,64,64,256]
  const float* Wq = (const float*)d_in[2];     // [256,128]
  const float* Wk = (const float*)d_in[3];     // [256,128]
  const float* Wv = (const float*)d_in[4];     // [256,128]
  const float* Wo = (const float*)d_in[5];     // [128,256]
  float* out = (float*)d_out;                  // [32768,256]

  float* ws = (float*)d_ws;
  float* M1 = ws;            // 65536 floats
  float* M2 = ws + 65536;    // 65536 floats
  float* QM = ws + 131072;   // 32768*256 floats  (ws needs ~32.5 MB)

  precompute_weights<<<512, 256, 0, stream>>>(Wq, Wk, Wv, Wo, M1, M2);
  gemm_32768x256x256<<<512, 256, 0, stream>>>(query, M1, QM);
  // hbar goes straight into d_out (same shape), saving workspace+traffic
  attn_main<<<8192, 256, 0, stream>>>(hist, QM, out);
  // out-projection in-place on d_out (block-local rows => safe)
  gemm_32768x256x256<<<512, 256, 0, stream>>>(out, M2, out);
}

// Round 2
// 275.337 us; speedup vs baseline: 1.2402x; 1.2402x over previous
//
#include <hip/hip_runtime.h>
#include <math.h>

// Shapes: B=8, T=16, H=64, W=64, D=256, DK=128, TOP_K=4
// pixels N = B*H*W = 32768 (4096 per batch)
//
// Factorization: out = (sum_t attn_t * hist_t) @ (Wv@Wo)
//                score_t = (q @ (Wq@Wk^T)) . hist_t / sqrt(128)
// => hist read exactly once (straight into registers: 16 t x float4/lane
//    = 64 VGPR per lane), score path fully fp32 (top-k is precision-critical).

// ---------------- Kernel P: M1 = Wq@Wk^T, M2 = Wv@Wo (256x256 each) -------
__global__ __launch_bounds__(256) void precompute_weights(
    const float* __restrict__ Wq, const float* __restrict__ Wk,
    const float* __restrict__ Wv, const float* __restrict__ Wo,
    float* __restrict__ M1, float* __restrict__ M2) {
  __shared__ float rowbuf[128];
  int bid = blockIdx.x, tid = threadIdx.x;
  if (bid < 256) {
    // M1[bid][j] = sum_k Wq[bid,k] * Wk[j,k]
    if (tid < 128) rowbuf[tid] = Wq[bid * 128 + tid];
    __syncthreads();
    const float4* Wk4 = (const float4*)Wk;
    const float4* rb4 = (const float4*)rowbuf;
    float acc = 0.f;
#pragma unroll 8
    for (int k4 = 0; k4 < 32; ++k4) {
      float4 a = rb4[k4];
      float4 b = Wk4[tid * 32 + k4];
      acc = fmaf(a.x, b.x, acc); acc = fmaf(a.y, b.y, acc);
      acc = fmaf(a.z, b.z, acc); acc = fmaf(a.w, b.w, acc);
    }
    M1[bid * 256 + tid] = acc;
  } else {
    // M2[d][e] = sum_k Wv[d,k] * Wo[k,e]
    int d = bid - 256;
    if (tid < 128) rowbuf[tid] = Wv[d * 128 + tid];
    __syncthreads();
    float acc = 0.f;
#pragma unroll 8
    for (int k = 0; k < 128; ++k)
      acc = fmaf(rowbuf[k], Wo[k * 256 + tid], acc);
    M2[d * 256 + tid] = acc;
  }
}

// ---------------- GEMM: C[32768x256] = A[32768x256] @ B[256x256] ----------
// 64 rows per block. In-place safe (A may equal C): tile is fully staged to
// LDS before any store, and each block touches only its own 64 rows.
__global__ __launch_bounds__(256) void gemm_32768x256x256(
    const float* A, const float* B, float* C) {
  __shared__ float As[64][257];  // stride 257: 2-way max bank aliasing (free)
  int tid = threadIdx.x;
  size_t r0 = (size_t)blockIdx.x * 64;
  const float* Ab = A + r0 * 256;
  for (int i = tid; i < 64 * 256; i += 256)
    As[i >> 8][i & 255] = Ab[i];
  __syncthreads();
  int ei = tid & 63;  // 4-col group
  int ri = tid >> 6;  // 16-row group
  float4 acc[16];
#pragma unroll
  for (int j = 0; j < 16; ++j) acc[j] = make_float4(0.f, 0.f, 0.f, 0.f);
  const float4* B4 = (const float4*)B;
#pragma unroll 4
  for (int d = 0; d < 256; ++d) {
    float4 bv = B4[d * 64 + ei];
#pragma unroll
    for (int j = 0; j < 16; ++j) {
      float a = As[ri * 16 + j][d];
      acc[j].x = fmaf(a, bv.x, acc[j].x);
      acc[j].y = fmaf(a, bv.y, acc[j].y);
      acc[j].z = fmaf(a, bv.z, acc[j].z);
      acc[j].w = fmaf(a, bv.w, acc[j].w);
    }
  }
  float4* C4 = (float4*)(C + r0 * 256);
#pragma unroll
  for (int j = 0; j < 16; ++j)
    C4[(ri * 16 + j) * 64 + ei] = acc[j];
}

// ---------------- Main: scores -> exact top-4 -> softmax -> hbar ----------
// Block = 256 thr (4 waves), one pixel per wave. NO LDS: hist tile lives in
// registers (16 x float4 per lane). Score reduce = 17-shuffle tree leaving
// score[t] at lane (l&15), replicated across the four 16-lane groups.
__global__ __launch_bounds__(256) void attn_main(
    const float* __restrict__ hist, const float* __restrict__ QM,
    float* __restrict__ HBAR) {
  int tid = threadIdx.x;
  int l = tid & 63;   // lane
  int p = tid >> 6;   // wave id == pixel within block
  int pix = blockIdx.x * 4 + p;
  int b = pix >> 12;      // 4096 pixels per batch
  int off = pix & 4095;   // h*64+w

  // hist[b, t, off, 4l..4l+3] for t=0..15 -> registers
  const float4* H4 = (const float4*)hist;
  size_t base = ((size_t)b * 16 * 4096 + off) * 64 + l;
  float4 h[16];
#pragma unroll
  for (int t = 0; t < 16; ++t)
    h[t] = H4[base + (size_t)t * (4096 * 64)];

  float4 q = ((const float4*)QM)[(size_t)pix * 64 + l];

  // partial dot per t (this lane's 4 dims)
  float part[16];
#pragma unroll
  for (int t = 0; t < 16; ++t) {
    float s = h[t].x * q.x;
    s = fmaf(h[t].y, q.y, s);
    s = fmaf(h[t].z, q.z, s);
    s = fmaf(h[t].w, q.w, s);
    part[t] = s;
  }
  // multi-value tree reduce: after 4 stages part[0] holds t=(l&15) summed
  // over this 16-lane group; two more butterflies finish the 64-lane sum.
#pragma unroll
  for (int s = 0; s < 4; ++s) {
    bool hi = (l >> s) & 1;
    int nt = 8 >> s;
#pragma unroll
    for (int i = 0; i < nt; ++i) {
      float mine = hi ? part[2 * i + 1] : part[2 * i];
      float oth  = hi ? part[2 * i]     : part[2 * i + 1];
      part[i] = mine + __shfl_xor(oth, 1 << s);
    }
  }
  float v = part[0];
  v += __shfl_xor(v, 16);
  v += __shfl_xor(v, 32);
  float sc = v * 0.08838834764831845f;  // 1/sqrt(128); t = l&15

  // ---- exact top-4 over the 16-lane group (lowest-index tie-break) ----
  unsigned long long grp = 0xFFFFull << (l & 48);
  float work = sc;
  bool chosen = false;
#pragma unroll
  for (int r = 0; r < 4; ++r) {
    float m = work;
    m = fmaxf(m, __shfl_xor(m, 1));
    m = fmaxf(m, __shfl_xor(m, 2));
    m = fmaxf(m, __shfl_xor(m, 4));
    m = fmaxf(m, __shfl_xor(m, 8));
    unsigned long long bal = __ballot(work == m) & grp;
    int sel = __ffsll(bal) - 1;  // absolute lane of lowest tied max
    if (l == sel) {
      chosen = true;
      work = -INFINITY;
    }
  }

  // ---- decay bias + softmax over the 4 chosen (within 16-lane group) ----
  int t_mine = l & 15;
  float bias = logf(powf(0.95f, (float)(16 - t_mine)) + 1e-10f);
  float earg = chosen ? (sc + bias) : -INFINITY;
  float M = earg;
  M = fmaxf(M, __shfl_xor(M, 1));
  M = fmaxf(M, __shfl_xor(M, 2));
  M = fmaxf(M, __shfl_xor(M, 4));
  M = fmaxf(M, __shfl_xor(M, 8));
  float ex = chosen ? expf(earg - M) : 0.0f;
  float Z = ex;
  Z += __shfl_xor(Z, 1);
  Z += __shfl_xor(Z, 2);
  Z += __shfl_xor(Z, 4);
  Z += __shfl_xor(Z, 8);
  float attn = ex / Z;  // attn for t = l&15, replicated per group

  // ---- hbar = sum_t attn[t] * hist[t] (registers; broadcast via shfl) ----
  float4 acc = make_float4(0.f, 0.f, 0.f, 0.f);
#pragma unroll
  for (int t = 0; t < 16; ++t) {
    float a = __shfl(attn, (l & 48) | t);  // read from own group's lane t
    acc.x = fmaf(a, h[t].x, acc.x);
    acc.y = fmaf(a, h[t].y, acc.y);
    acc.z = fmaf(a, h[t].z, acc.z);
    acc.w = fmaf(a, h[t].w, acc.w);
  }
  ((float4*)HBAR)[(size_t)pix * 64 + l] = acc;
}

// --------------------------------------------------------------------------
extern "C" void kernel_launch(void* const* d_in, const int* in_sizes, int n_in,
                              void* d_out, int out_size, void* d_ws,
                              size_t ws_size, hipStream_t stream) {
  const float* query = (const float*)d_in[0];  // [8,64,64,256]
  const float* hist = (const float*)d_in[1];   // [8,16,64,64,256]
  const float* Wq = (const float*)d_in[2];     // [256,128]
  const float* Wk = (const float*)d_in[3];     // [256,128]
  const float* Wv = (const float*)d_in[4];     // [256,128]
  const float* Wo = (const float*)d_in[5];     // [128,256]
  float* out = (float*)d_out;                  // [32768,256]

  float* ws = (float*)d_ws;
  float* M1 = ws;           // 65536 floats
  float* M2 = ws + 65536;   // 65536 floats
  float* QM = ws + 131072;  // 32768*256 floats (ws ~32.5 MB)

  precompute_weights<<<512, 256, 0, stream>>>(Wq, Wk, Wv, Wo, M1, M2);
  gemm_32768x256x256<<<512, 256, 0, stream>>>(query, M1, QM);
  // hbar straight into d_out, then out-projection in-place (block-local rows)
  attn_main<<<8192, 256, 0, stream>>>(hist, QM, out);
  gemm_32768x256x256<<<512, 256, 0, stream>>>(out, M2, out);
}

// Round 3
// 244.961 us; speedup vs baseline: 1.3939x; 1.1240x over previous
//
#include <hip/hip_runtime.h>
#include <math.h>

// Shapes: B=8, T=16, H=64, W=64, D=256, DK=128, TOP_K=4
// pixels N = B*H*W = 32768 (4096 per batch)
//
// Factorization: out = (sum_t attn_t * hist_t) @ (Wv@Wo)
//                score_t = (q @ (Wq@Wk^T)) . hist_t / sqrt(128)
// hist read exactly once, straight into registers (16 x float4 / lane).
// Score path fully fp32 (top-k selection is precision-critical).
// Out-projection fused: hbar -> LDS tile -> 64-row GEMM vs M2 in-block.

// ---------------- Kernel P: M1 = Wq@Wk^T, M2 = Wv@Wo (256x256 each) -------
__global__ __launch_bounds__(256) void precompute_weights(
    const float* __restrict__ Wq, const float* __restrict__ Wk,
    const float* __restrict__ Wv, const float* __restrict__ Wo,
    float* __restrict__ M1, float* __restrict__ M2) {
  __shared__ float rowbuf[128];
  int bid = blockIdx.x, tid = threadIdx.x;
  if (bid < 256) {
    if (tid < 128) rowbuf[tid] = Wq[bid * 128 + tid];
    __syncthreads();
    const float4* Wk4 = (const float4*)Wk;
    const float4* rb4 = (const float4*)rowbuf;
    float acc = 0.f;
#pragma unroll 8
    for (int k4 = 0; k4 < 32; ++k4) {
      float4 a = rb4[k4];
      float4 b = Wk4[tid * 32 + k4];
      acc = fmaf(a.x, b.x, acc); acc = fmaf(a.y, b.y, acc);
      acc = fmaf(a.z, b.z, acc); acc = fmaf(a.w, b.w, acc);
    }
    M1[bid * 256 + tid] = acc;
  } else {
    int d = bid - 256;
    if (tid < 128) rowbuf[tid] = Wv[d * 128 + tid];
    __syncthreads();
    float acc = 0.f;
#pragma unroll 8
    for (int k = 0; k < 128; ++k)
      acc = fmaf(rowbuf[k], Wo[k * 256 + tid], acc);
    M2[d * 256 + tid] = acc;
  }
}

// ---------------- GEMM: QM[32768x256] = query @ M1 ------------------------
__global__ __launch_bounds__(256) void gemm_32768x256x256(
    const float* A, const float* B, float* C) {
  __shared__ float As[64][257];
  int tid = threadIdx.x;
  size_t r0 = (size_t)blockIdx.x * 64;
  const float* Ab = A + r0 * 256;
  for (int i = tid; i < 64 * 256; i += 256)
    As[i >> 8][i & 255] = Ab[i];
  __syncthreads();
  int ei = tid & 63;
  int ri = tid >> 6;
  float4 acc[16];
#pragma unroll
  for (int j = 0; j < 16; ++j) acc[j] = make_float4(0.f, 0.f, 0.f, 0.f);
  const float4* B4 = (const float4*)B;
#pragma unroll 4
  for (int d = 0; d < 256; ++d) {
    float4 bv = B4[d * 64 + ei];
#pragma unroll
    for (int j = 0; j < 16; ++j) {
      float a = As[ri * 16 + j][d];
      acc[j].x = fmaf(a, bv.x, acc[j].x);
      acc[j].y = fmaf(a, bv.y, acc[j].y);
      acc[j].z = fmaf(a, bv.z, acc[j].z);
      acc[j].w = fmaf(a, bv.w, acc[j].w);
    }
  }
  float4* C4 = (float4*)(C + r0 * 256);
#pragma unroll
  for (int j = 0; j < 16; ++j)
    C4[(ri * 16 + j) * 64 + ei] = acc[j];
}

// ---------------- Fused: attention (64 pixels/block) + out-projection -----
// Phase 1: wave w handles pixels w*16+it, it=0..15. Per pixel: hist tile in
// regs, score reduce (17 shuffles), rank-based top-4 (15 independent
// shuffles), biased softmax, hbar -> LDS row.
// Phase 2: 64-row GEMM  OUT[tile] = As(64x256) @ M2(256x256).
__global__ __launch_bounds__(256) void attn_out_fused(
    const float* __restrict__ hist, const float* __restrict__ QM,
    const float* __restrict__ M2, float* __restrict__ OUT) {
  __shared__ float As[64][260];  // hbar tile; row*260 floats, 16B-aligned rows
  int tid = threadIdx.x;
  int l = tid & 63;
  int w = tid >> 6;
  int pix0 = blockIdx.x * 64;
  const float4* H4 = (const float4*)hist;
  const float4* QM4 = (const float4*)QM;
  int t_mine = l & 15;
  int gbase = l & 48;  // 16-lane replica group base

  for (int it = 0; it < 16; ++it) {
    int row = w * 16 + it;
    int pix = pix0 + row;
    int b = pix >> 12;
    int off = pix & 4095;

    size_t base = ((size_t)b * 16 * 4096 + off) * 64 + l;
    float4 h[16];
#pragma unroll
    for (int t = 0; t < 16; ++t)
      h[t] = H4[base + (size_t)t * (4096 * 64)];
    float4 q = QM4[(size_t)pix * 64 + l];

    float part[16];
#pragma unroll
    for (int t = 0; t < 16; ++t) {
      float s = h[t].x * q.x;
      s = fmaf(h[t].y, q.y, s);
      s = fmaf(h[t].z, q.z, s);
      s = fmaf(h[t].w, q.w, s);
      part[t] = s;
    }
    // tree reduce: part[0] -> group-partial for t = l&15
#pragma unroll
    for (int s = 0; s < 4; ++s) {
      bool hi = (l >> s) & 1;
      int nt = 8 >> s;
#pragma unroll
      for (int i = 0; i < nt; ++i) {
        float mine = hi ? part[2 * i + 1] : part[2 * i];
        float oth  = hi ? part[2 * i]     : part[2 * i + 1];
        part[i] = mine + __shfl_xor(oth, 1 << s);
      }
    }
    float v = part[0];
    v += __shfl_xor(v, 16);
    v += __shfl_xor(v, 32);
    float sc = v * 0.08838834764831845f;  // full dot for t=l&15, replicated

    // rank-based exact top-4 (lowest-index tie-break == lax.top_k)
    int rank = 0;
#pragma unroll
    for (int k = 1; k < 16; ++k) {
      int ot = (t_mine + k) & 15;
      float o = __shfl(sc, gbase | ot);
      rank += (o > sc) || (o == sc && ot < t_mine);
    }
    bool chosen = rank < 4;

    // decay bias + softmax over the 4 chosen (no max-sub: |sc| small)
    float earg = sc + (float)(16 - t_mine) * -0.05129329438755058f;
    float ex = chosen ? expf(earg) : 0.0f;
    float Z = ex;
    Z += __shfl_xor(Z, 1);
    Z += __shfl_xor(Z, 2);
    Z += __shfl_xor(Z, 4);
    Z += __shfl_xor(Z, 8);
    float attn = ex / Z;  // weight for t=l&15, replicated per group

    // hbar = sum_t attn[t] * h[t]
    float4 acc = make_float4(0.f, 0.f, 0.f, 0.f);
#pragma unroll
    for (int t = 0; t < 16; ++t) {
      float a = __shfl(attn, gbase | t);  // wave-uniform per t
      if (a != 0.0f) {
        acc.x = fmaf(a, h[t].x, acc.x);
        acc.y = fmaf(a, h[t].y, acc.y);
        acc.z = fmaf(a, h[t].z, acc.z);
        acc.w = fmaf(a, h[t].w, acc.w);
      }
    }
    *(float4*)&As[row][4 * l] = acc;  // contiguous 1KB row write
  }
  __syncthreads();

  // ---- phase 2: OUT rows pix0..pix0+63 = As @ M2 ----
  int ei = tid & 63;
  int ri = tid >> 6;
  float4 acc[16];
#pragma unroll
  for (int j = 0; j < 16; ++j) acc[j] = make_float4(0.f, 0.f, 0.f, 0.f);
  const float4* B4 = (const float4*)M2;
#pragma unroll 4
  for (int d = 0; d < 256; ++d) {
    float4 bv = B4[d * 64 + ei];
#pragma unroll
    for (int j = 0; j < 16; ++j) {
      float a = As[ri * 16 + j][d];  // uniform addr -> broadcast
      acc[j].x = fmaf(a, bv.x, acc[j].x);
      acc[j].y = fmaf(a, bv.y, acc[j].y);
      acc[j].z = fmaf(a, bv.z, acc[j].z);
      acc[j].w = fmaf(a, bv.w, acc[j].w);
    }
  }
  float4* C4 = (float4*)(OUT + (size_t)pix0 * 256);
#pragma unroll
  for (int j = 0; j < 16; ++j)
    C4[(ri * 16 + j) * 64 + ei] = acc[j];
}

// --------------------------------------------------------------------------
extern "C" void kernel_launch(void* const* d_in, const int* in_sizes, int n_in,
                              void* d_out, int out_size, void* d_ws,
                              size_t ws_size, hipStream_t stream) {
  const float* query = (const float*)d_in[0];  // [8,64,64,256]
  const float* hist = (const float*)d_in[1];   // [8,16,64,64,256]
  const float* Wq = (const float*)d_in[2];     // [256,128]
  const float* Wk = (const float*)d_in[3];     // [256,128]
  const float* Wv = (const float*)d_in[4];     // [256,128]
  const float* Wo = (const float*)d_in[5];     // [128,256]
  float* out = (float*)d_out;                  // [32768,256]

  float* ws = (float*)d_ws;
  float* M1 = ws;           // 65536 floats
  float* M2 = ws + 65536;   // 65536 floats
  float* QM = ws + 131072;  // 32768*256 floats (ws ~32.5 MB)

  precompute_weights<<<512, 256, 0, stream>>>(Wq, Wk, Wv, Wo, M1, M2);
  gemm_32768x256x256<<<512, 256, 0, stream>>>(query, M1, QM);
  attn_out_fused<<<512, 256, 0, stream>>>(hist, QM, M2, out);
}

// Round 4
// 203.855 us; speedup vs baseline: 1.6750x; 1.2016x over previous
//
#include <hip/hip_runtime.h>
#include <math.h>

// Shapes: B=8, T=16, H=64, W=64, D=256, DK=128, TOP_K=4
// pixels N = B*H*W = 32768 (4096 per batch)
//
// Factorization: out = (sum_t attn_t * hist_t) @ (Wv@Wo)
//                score_t = (q @ (Wq@Wk^T)) . hist_t / sqrt(128)
// hist read exactly once, double-buffered in registers (2 x 16 float4/lane)
// so pixel i+1's loads fly under pixel i's score/softmax chain.
// Score path fully fp32 (top-k selection is precision-critical).
// Single mega-kernel: phase0 qm=query@M1 -> phase1 attention -> phase2 @M2,
// all sharing one 64x260 LDS tile (row-exclusive ownership between syncs).

// ---------------- Kernel P: M1 = Wq@Wk^T, M2 = Wv@Wo (256x256 each) -------
__global__ __launch_bounds__(256) void precompute_weights(
    const float* __restrict__ Wq, const float* __restrict__ Wk,
    const float* __restrict__ Wv, const float* __restrict__ Wo,
    float* __restrict__ M1, float* __restrict__ M2) {
  __shared__ float rowbuf[128];
  int bid = blockIdx.x, tid = threadIdx.x;
  if (bid < 256) {
    if (tid < 128) rowbuf[tid] = Wq[bid * 128 + tid];
    __syncthreads();
    const float4* Wk4 = (const float4*)Wk;
    const float4* rb4 = (const float4*)rowbuf;
    float acc = 0.f;
#pragma unroll 8
    for (int k4 = 0; k4 < 32; ++k4) {
      float4 a = rb4[k4];
      float4 b = Wk4[tid * 32 + k4];
      acc = fmaf(a.x, b.x, acc); acc = fmaf(a.y, b.y, acc);
      acc = fmaf(a.z, b.z, acc); acc = fmaf(a.w, b.w, acc);
    }
    M1[bid * 256 + tid] = acc;
  } else {
    int d = bid - 256;
    if (tid < 128) rowbuf[tid] = Wv[d * 128 + tid];
    __syncthreads();
    float acc = 0.f;
#pragma unroll 8
    for (int k = 0; k < 128; ++k)
      acc = fmaf(rowbuf[k], Wo[k * 256 + tid], acc);
    M2[d * 256 + tid] = acc;
  }
}

// ---------------- Mega-kernel: qm -> attention -> out-projection ----------
__global__ __launch_bounds__(256, 2) void fused_all(
    const float* __restrict__ query, const float* __restrict__ hist,
    const float* __restrict__ M1, const float* __restrict__ M2,
    float* __restrict__ OUT) {
  __shared__ float As[64][260];  // query tile -> qm tile -> hbar tile
  int tid = threadIdx.x;
  int l = tid & 63;   // lane
  int w = tid >> 6;   // wave
  int pix0 = blockIdx.x * 64;

  // ---------- phase 0: As <- (query tile) @ M1  (qm, fp32) ----------
  {
    const float* Qb = query + (size_t)pix0 * 256;
    for (int i = tid; i < 64 * 256; i += 256)
      As[i >> 8][i & 255] = Qb[i];
    __syncthreads();
    float4 acc[16];
#pragma unroll
    for (int j = 0; j < 16; ++j) acc[j] = make_float4(0.f, 0.f, 0.f, 0.f);
    const float4* B4 = (const float4*)M1;
#pragma unroll 4
    for (int d = 0; d < 256; ++d) {
      float4 bv = B4[d * 64 + l];
#pragma unroll
      for (int j = 0; j < 16; ++j) {
        float a = As[w * 16 + j][d];  // uniform -> broadcast
        acc[j].x = fmaf(a, bv.x, acc[j].x);
        acc[j].y = fmaf(a, bv.y, acc[j].y);
        acc[j].z = fmaf(a, bv.z, acc[j].z);
        acc[j].w = fmaf(a, bv.w, acc[j].w);
      }
    }
    __syncthreads();  // all reads of query tile done before overwrite
#pragma unroll
    for (int j = 0; j < 16; ++j)
      *(float4*)&As[w * 16 + j][4 * l] = acc[j];
    __syncthreads();
  }

  // ---------- phase 1: stream hist, score, top-4, softmax, hbar ----------
  const float4* H4 = (const float4*)hist;
  int b = pix0 >> 12;      // 64-pixel tile never crosses a batch (4096 % 64 == 0)
  int off0 = pix0 & 4095;
  int t_mine = l & 15;
  int gbase = l & 48;  // 16-lane replica group base
  // float4-unit base: pixel (off0+row), time t -> hblk + row*64 + t*262144
  size_t hblk = ((size_t)b * 16 * 4096 + off0) * 64 + l;

  float4 hA[16], hB[16];
#pragma unroll
  for (int t = 0; t < 16; ++t)
    hA[t] = H4[hblk + (size_t)(w * 16) * 64 + (size_t)t * 262144];

#define ATTN_STEP(HC, HN, IT, DOPRE)                                        \
  {                                                                         \
    int row = w * 16 + (IT);                                                \
    if (DOPRE) { /* prefetch next pixel into HN while computing HC */       \
      size_t nb = hblk + (size_t)(row + 1) * 64;                            \
      _Pragma("unroll") for (int t = 0; t < 16; ++t)                        \
          HN[t] = H4[nb + (size_t)t * 262144];                              \
    }                                                                       \
    float4 q = *(const float4*)&As[row][4 * l];                             \
    float part[16];                                                         \
    _Pragma("unroll") for (int t = 0; t < 16; ++t) {                        \
      float s = HC[t].x * q.x;                                              \
      s = fmaf(HC[t].y, q.y, s);                                            \
      s = fmaf(HC[t].z, q.z, s);                                            \
      s = fmaf(HC[t].w, q.w, s);                                            \
      part[t] = s;                                                          \
    }                                                                       \
    _Pragma("unroll") for (int st = 0; st < 4; ++st) {                      \
      bool hi = (l >> st) & 1;                                              \
      int nt = 8 >> st;                                                     \
      _Pragma("unroll") for (int i = 0; i < nt; ++i) {                      \
        float mine = hi ? part[2 * i + 1] : part[2 * i];                    \
        float oth = hi ? part[2 * i] : part[2 * i + 1];                     \
        part[i] = mine + __shfl_xor(oth, 1 << st);                          \
      }                                                                     \
    }                                                                       \
    float v = part[0];                                                      \
    v += __shfl_xor(v, 16);                                                 \
    v += __shfl_xor(v, 32);                                                 \
    float sc = v * 0.08838834764831845f; /* 1/sqrt(128); t = l&15 */        \
    int rank = 0; /* exact lax.top_k: lowest-index tie-break */             \
    _Pragma("unroll") for (int k = 1; k < 16; ++k) {                        \
      int ot = (t_mine + k) & 15;                                           \
      float o = __shfl(sc, gbase | ot);                                     \
      rank += (o > sc) || (o == sc && ot < t_mine);                         \
    }                                                                       \
    bool chosen = rank < 4;                                                 \
    float earg = sc + (float)(16 - t_mine) * -0.05129329438755058f;         \
    float ex = chosen ? expf(earg) : 0.0f;                                  \
    float Z = ex;                                                           \
    Z += __shfl_xor(Z, 1);                                                  \
    Z += __shfl_xor(Z, 2);                                                  \
    Z += __shfl_xor(Z, 4);                                                  \
    Z += __shfl_xor(Z, 8);                                                  \
    float attn = ex / Z;                                                    \
    float4 hb = make_float4(0.f, 0.f, 0.f, 0.f);                            \
    _Pragma("unroll") for (int t = 0; t < 16; ++t) {                        \
      float a = __shfl(attn, gbase | t); /* uniform in value across wave */ \
      if (a != 0.0f) {                                                      \
        hb.x = fmaf(a, HC[t].x, hb.x);                                      \
        hb.y = fmaf(a, HC[t].y, hb.y);                                      \
        hb.z = fmaf(a, HC[t].z, hb.z);                                      \
        hb.w = fmaf(a, HC[t].w, hb.w);                                      \
      }                                                                     \
    }                                                                       \
    *(float4*)&As[row][4 * l] = hb; /* q already in reg; row wave-owned */  \
  }

  for (int it2 = 0; it2 < 8; ++it2) {
    ATTN_STEP(hA, hB, 2 * it2, true);
    ATTN_STEP(hB, hA, 2 * it2 + 1, it2 < 7);
  }
#undef ATTN_STEP
  __syncthreads();

  // ---------- phase 2: OUT rows pix0..pix0+63 = As(hbar) @ M2 ----------
  {
    float4 acc[16];
#pragma unroll
    for (int j = 0; j < 16; ++j) acc[j] = make_float4(0.f, 0.f, 0.f, 0.f);
    const float4* B4 = (const float4*)M2;
#pragma unroll 4
    for (int d = 0; d < 256; ++d) {
      float4 bv = B4[d * 64 + l];
#pragma unroll
      for (int j = 0; j < 16; ++j) {
        float a = As[w * 16 + j][d];  // uniform -> broadcast
        acc[j].x = fmaf(a, bv.x, acc[j].x);
        acc[j].y = fmaf(a, bv.y, acc[j].y);
        acc[j].z = fmaf(a, bv.z, acc[j].z);
        acc[j].w = fmaf(a, bv.w, acc[j].w);
      }
    }
    float4* C4 = (float4*)(OUT + (size_t)pix0 * 256);
#pragma unroll
    for (int j = 0; j < 16; ++j)
      C4[(w * 16 + j) * 64 + l] = acc[j];
  }
}

// --------------------------------------------------------------------------
extern "C" void kernel_launch(void* const* d_in, const int* in_sizes, int n_in,
                              void* d_out, int out_size, void* d_ws,
                              size_t ws_size, hipStream_t stream) {
  const float* query = (const float*)d_in[0];  // [8,64,64,256]
  const float* hist = (const float*)d_in[1];   // [8,16,64,64,256]
  const float* Wq = (const float*)d_in[2];     // [256,128]
  const float* Wk = (const float*)d_in[3];     // [256,128]
  const float* Wv = (const float*)d_in[4];     // [256,128]
  const float* Wo = (const float*)d_in[5];     // [128,256]
  float* out = (float*)d_out;                  // [32768,256]

  float* ws = (float*)d_ws;
  float* M1 = ws;          // 65536 floats
  float* M2 = ws + 65536;  // 65536 floats (ws needs only 512 KB now)

  precompute_weights<<<512, 256, 0, stream>>>(Wq, Wk, Wv, Wo, M1, M2);
  fused_all<<<512, 256, 0, stream>>>(query, hist, M1, M2, out);
}

// Round 5
// 202.517 us; speedup vs baseline: 1.6861x; 1.0066x over previous
//
#include <hip/hip_runtime.h>
#include <math.h>

// Shapes: B=8, T=16, H=64, W=64, D=256, DK=128, TOP_K=4
// pixels N = B*H*W = 32768 (4096 per batch)
//
// Factorization: out = (sum_t attn_t * hist_t) @ (Wv@Wo)
//                score_t = (q @ (Wq@Wk^T)) . hist_t / sqrt(128)
// hist read exactly once, double-buffered in registers.
// Score path fully fp32 (top-k selection is precision-critical).
//
// R5 structure: the mega-kernel is BARRIER-FREE. Each wave owns 16 rows of
// the LDS tile end-to-end (phase0 qm GEMM -> phase1 attention -> phase2 out
// GEMM), so the 8 resident waves/CU de-phase naturally and one wave's
// VALU-dense GEMM overlaps another's HBM-dense hist stream.

// ---------------- Kernel P: M1 = Wq@Wk^T, M2 = Wv@Wo (256x256 each) -------
__global__ __launch_bounds__(256) void precompute_weights(
    const float* __restrict__ Wq, const float* __restrict__ Wk,
    const float* __restrict__ Wv, const float* __restrict__ Wo,
    float* __restrict__ M1, float* __restrict__ M2) {
  __shared__ float rowbuf[128];
  int bid = blockIdx.x, tid = threadIdx.x;
  if (bid < 256) {
    if (tid < 128) rowbuf[tid] = Wq[bid * 128 + tid];
    __syncthreads();
    const float4* Wk4 = (const float4*)Wk;
    const float4* rb4 = (const float4*)rowbuf;
    float acc = 0.f;
#pragma unroll 8
    for (int k4 = 0; k4 < 32; ++k4) {
      float4 a = rb4[k4];
      float4 b = Wk4[tid * 32 + k4];
      acc = fmaf(a.x, b.x, acc); acc = fmaf(a.y, b.y, acc);
      acc = fmaf(a.z, b.z, acc); acc = fmaf(a.w, b.w, acc);
    }
    M1[bid * 256 + tid] = acc;
  } else {
    int d = bid - 256;
    if (tid < 128) rowbuf[tid] = Wv[d * 128 + tid];
    __syncthreads();
    float acc = 0.f;
#pragma unroll 8
    for (int k = 0; k < 128; ++k)
      acc = fmaf(rowbuf[k], Wo[k * 256 + tid], acc);
    M2[d * 256 + tid] = acc;
  }
}

// ---------------- Mega-kernel: qm -> attention -> out-projection ----------
// 64 pixels/block, 4 waves, wave w owns rows w*16..w*16+15. NO barriers.
__global__ __launch_bounds__(256, 2) void fused_all(
    const float* __restrict__ query, const float* __restrict__ hist,
    const float* __restrict__ M1, const float* __restrict__ M2,
    float* __restrict__ OUT) {
  __shared__ float As[64][260];  // per-wave 16-row slice: query->qm->hbar
  int tid = threadIdx.x;
  int l = tid & 63;   // lane
  int w = tid >> 6;   // wave
  int pix0 = blockIdx.x * 64;
  int r0 = w * 16;    // this wave's first row

  // ---------- phase 0: own 16 rows of qm = query @ M1 (fp32) ----------
  {
    const float4* Qb4 = (const float4*)(query + (size_t)pix0 * 256);
#pragma unroll
    for (int k = 0; k < 16; ++k)  // stage own rows (1KB contiguous each)
      *(float4*)&As[r0 + k][4 * l] = Qb4[(size_t)(r0 + k) * 64 + l];
    float4 acc[16];
#pragma unroll
    for (int j = 0; j < 16; ++j) acc[j] = make_float4(0.f, 0.f, 0.f, 0.f);
    const float4* B4 = (const float4*)M1;
#pragma unroll 4
    for (int d = 0; d < 256; ++d) {
      float4 bv = B4[d * 64 + l];
#pragma unroll
      for (int j = 0; j < 16; ++j) {
        float a = As[r0 + j][d];  // uniform -> LDS broadcast
        acc[j].x = fmaf(a, bv.x, acc[j].x);
        acc[j].y = fmaf(a, bv.y, acc[j].y);
        acc[j].z = fmaf(a, bv.z, acc[j].z);
        acc[j].w = fmaf(a, bv.w, acc[j].w);
      }
    }
    // all reads of query slice done (program order) -> overwrite with qm
#pragma unroll
    for (int j = 0; j < 16; ++j)
      *(float4*)&As[r0 + j][4 * l] = acc[j];
  }

  // ---------- phase 1: stream hist, score, top-4, softmax, hbar ----------
  const float4* H4 = (const float4*)hist;
  int b = pix0 >> 12;  // 64-pixel tile never crosses a batch
  int off0 = pix0 & 4095;
  int t_mine = l & 15;
  int gbase = l & 48;  // 16-lane replica group base
  size_t hblk = ((size_t)b * 16 * 4096 + off0) * 64 + l;

  float4 hA[16], hB[16];
#pragma unroll
  for (int t = 0; t < 16; ++t)
    hA[t] = H4[hblk + (size_t)r0 * 64 + (size_t)t * 262144];

#define ATTN_STEP(HC, HN, IT, DOPRE)                                        \
  {                                                                         \
    int row = r0 + (IT);                                                    \
    if (DOPRE) { /* prefetch next pixel into HN while computing HC */       \
      size_t nb = hblk + (size_t)(row + 1) * 64;                            \
      _Pragma("unroll") for (int t = 0; t < 16; ++t)                        \
          HN[t] = H4[nb + (size_t)t * 262144];                              \
    }                                                                       \
    float4 q = *(const float4*)&As[row][4 * l];                             \
    float part[16];                                                         \
    _Pragma("unroll") for (int t = 0; t < 16; ++t) {                        \
      float s = HC[t].x * q.x;                                              \
      s = fmaf(HC[t].y, q.y, s);                                            \
      s = fmaf(HC[t].z, q.z, s);                                            \
      s = fmaf(HC[t].w, q.w, s);                                            \
      part[t] = s;                                                          \
    }                                                                       \
    _Pragma("unroll") for (int st = 0; st < 4; ++st) {                      \
      bool hi = (l >> st) & 1;                                              \
      int nt = 8 >> st;                                                     \
      _Pragma("unroll") for (int i = 0; i < nt; ++i) {                      \
        float mine = hi ? part[2 * i + 1] : part[2 * i];                    \
        float oth = hi ? part[2 * i] : part[2 * i + 1];                     \
        part[i] = mine + __shfl_xor(oth, 1 << st);                          \
      }                                                                     \
    }                                                                       \
    float v = part[0];                                                      \
    v += __shfl_xor(v, 16);                                                 \
    v += __shfl_xor(v, 32);                                                 \
    float sc = v * 0.08838834764831845f; /* 1/sqrt(128); t = l&15 */        \
    int rank = 0; /* exact lax.top_k: lowest-index tie-break */             \
    _Pragma("unroll") for (int k = 1; k < 16; ++k) {                        \
      int ot = (t_mine + k) & 15;                                           \
      float o = __shfl(sc, gbase | ot);                                     \
      rank += (o > sc) || (o == sc && ot < t_mine);                         \
    }                                                                       \
    bool chosen = rank < 4;                                                 \
    float earg = sc + (float)(16 - t_mine) * -0.05129329438755058f;         \
    float ex = chosen ? expf(earg) : 0.0f;                                  \
    float Z = ex;                                                           \
    Z += __shfl_xor(Z, 1);                                                  \
    Z += __shfl_xor(Z, 2);                                                  \
    Z += __shfl_xor(Z, 4);                                                  \
    Z += __shfl_xor(Z, 8);                                                  \
    float attn = ex / Z;                                                    \
    float4 hb = make_float4(0.f, 0.f, 0.f, 0.f);                            \
    _Pragma("unroll") for (int t = 0; t < 16; ++t) {                        \
      float a = __shfl(attn, gbase | t); /* uniform in value across wave */ \
      if (a != 0.0f) {                                                      \
        hb.x = fmaf(a, HC[t].x, hb.x);                                      \
        hb.y = fmaf(a, HC[t].y, hb.y);                                      \
        hb.z = fmaf(a, HC[t].z, hb.z);                                      \
        hb.w = fmaf(a, HC[t].w, hb.w);                                      \
      }                                                                     \
    }                                                                       \
    *(float4*)&As[row][4 * l] = hb; /* q already in reg; row wave-owned */  \
  }

  for (int it2 = 0; it2 < 8; ++it2) {
    ATTN_STEP(hA, hB, 2 * it2, true);
    ATTN_STEP(hB, hA, 2 * it2 + 1, it2 < 7);
  }
#undef ATTN_STEP

  // ---------- phase 2: own 16 rows of OUT = As(hbar) @ M2 ----------
  {
    float4 acc[16];
#pragma unroll
    for (int j = 0; j < 16; ++j) acc[j] = make_float4(0.f, 0.f, 0.f, 0.f);
    const float4* B4 = (const float4*)M2;
#pragma unroll 4
    for (int d = 0; d < 256; ++d) {
      float4 bv = B4[d * 64 + l];
#pragma unroll
      for (int j = 0; j < 16; ++j) {
        float a = As[r0 + j][d];  // uniform -> LDS broadcast
        acc[j].x = fmaf(a, bv.x, acc[j].x);
        acc[j].y = fmaf(a, bv.y, acc[j].y);
        acc[j].z = fmaf(a, bv.z, acc[j].z);
        acc[j].w = fmaf(a, bv.w, acc[j].w);
      }
    }
    float4* C4 = (float4*)(OUT + (size_t)pix0 * 256);
#pragma unroll
    for (int j = 0; j < 16; ++j)
      C4[(r0 + j) * 64 + l] = acc[j];
  }
}

// --------------------------------------------------------------------------
extern "C" void kernel_launch(void* const* d_in, const int* in_sizes, int n_in,
                              void* d_out, int out_size, void* d_ws,
                              size_t ws_size, hipStream_t stream) {
  const float* query = (const float*)d_in[0];  // [8,64,64,256]
  const float* hist = (const float*)d_in[1];   // [8,16,64,64,256]
  const float* Wq = (const float*)d_in[2];     // [256,128]
  const float* Wk = (const float*)d_in[3];     // [256,128]
  const float* Wv = (const float*)d_in[4];     // [256,128]
  const float* Wo = (const float*)d_in[5];     // [128,256]
  float* out = (float*)d_out;                  // [32768,256]

  float* ws = (float*)d_ws;
  float* M1 = ws;          // 65536 floats
  float* M2 = ws + 65536;  // 65536 floats

  precompute_weights<<<512, 256, 0, stream>>>(Wq, Wk, Wv, Wo, M1, M2);
  fused_all<<<512, 256, 0, stream>>>(query, hist, M1, M2, out);
}